// Round 1
// baseline (168.551 us; speedup 1.0000x reference)
//
#include <hip/hip_runtime.h>
#include <cstdint>
#include <cstddef>

#define HF 128   // hidden feature dim
#define NTY 8    // edge types

// ---------------------------------------------------------------------------
// global -> LDS direct copy, 16B per lane (wave-uniform LDS base + lane*16)
// ---------------------------------------------------------------------------
__device__ __forceinline__ void gload_lds16(const float* g, float* l) {
  __builtin_amdgcn_global_load_lds(
      (const __attribute__((address_space(1))) void*)g,
      (__attribute__((address_space(3))) void*)l, 16, 0, 0);
}

// ---------------------------------------------------------------------------
// Kernel A: PQ[n][j]  (j<128: P = h@W1a.T + b1,  j>=128: Q = h@W1b.T)
//   tile: 32 nodes x 256 outs, 256 threads, per-thread 2 nodes x 16 outs.
//   LDS: W rearranged [256 out][128 k] XOR-swizzled (128KB, staged once)
//        A h-tile    [32 node][128 k] XOR-swizzled (16KB, staged per tile)
// ---------------------------------------------------------------------------
__global__ __launch_bounds__(256, 1) void node_pq_kernel(
    const float* __restrict__ h, const float* __restrict__ W1,
    const float* __restrict__ b1, float* __restrict__ PQ,
    int n_nodes, int n_tiles)
{
  __shared__ float Wl[256 * HF];  // 131072 B
  __shared__ float Al[32 * HF];   //  16384 B
  const int t    = threadIdx.x;
  const int lane = t & 63;
  const int wb   = t & 192;       // wave base within the 256-thread block

  // ---- stage rearranged W1 once (pre-swizzled global source) ----
#pragma unroll
  for (int i = 0; i < 32; ++i) {
    const int s  = i * 256 + wb + lane;   // 16B slot id, 0..8191
    const int j  = s >> 5;                // out row 0..255
    const int cs = (s & 31) ^ (j & 7);    // inverse-swizzled k-quad
    const float* g = (j < HF) ? (W1 + (size_t)j * 256 + cs * 4)
                              : (W1 + (size_t)(j - HF) * 256 + HF + cs * 4);
    gload_lds16(g, Wl + (size_t)(i * 256 + wb) * 4);
  }

  const int og = t & 15;   // out group: j = og + 16*jj
  const int pr = t >> 4;   // node-pair 0..15
  const int n0 = 2 * pr, n1 = n0 + 1;

  float bias[16];
#pragma unroll
  for (int jj = 0; jj < 16; ++jj) {
    const int j = og + 16 * jj;
    bias[jj] = (j < HF) ? b1[j] : 0.0f;
  }

  for (int tile = blockIdx.x; tile < n_tiles; tile += gridDim.x) {
    __syncthreads();  // previous tile's compute done before overwriting Al
#pragma unroll
    for (int i = 0; i < 4; ++i) {
      const int s = i * 256 + wb + lane;  // 0..1023
      const int r = s >> 5;               // tile row 0..31
      int node = tile * 32 + r;
      if (node >= n_nodes) node = n_nodes - 1;
      const int cs = (s & 31) ^ (r & 7);
      gload_lds16(h + (size_t)node * HF + cs * 4,
                  Al + (size_t)(i * 256 + wb) * 4);
    }
    __syncthreads();  // drains vmcnt -> LDS tiles valid

    float acc0[16], acc1[16];
#pragma unroll
    for (int jj = 0; jj < 16; ++jj) { acc0[jj] = bias[jj]; acc1[jj] = bias[jj]; }

#pragma unroll 2
    for (int c = 0; c < 32; ++c) {
      const float4 a0 = *(const float4*)(Al + n0 * HF + 4 * (c ^ (n0 & 7)));
      const float4 a1 = *(const float4*)(Al + n1 * HF + 4 * (c ^ (n1 & 7)));
#pragma unroll
      for (int jj = 0; jj < 16; ++jj) {
        const int j = og + 16 * jj;
        const float4 b = *(const float4*)(Wl + j * HF + 4 * (c ^ (j & 7)));
        acc0[jj] = fmaf(a0.w, b.w, fmaf(a0.z, b.z, fmaf(a0.y, b.y, fmaf(a0.x, b.x, acc0[jj]))));
        acc1[jj] = fmaf(a1.w, b.w, fmaf(a1.z, b.z, fmaf(a1.y, b.y, fmaf(a1.x, b.x, acc1[jj]))));
      }
    }

    const int g0 = tile * 32 + n0, g1 = g0 + 1;
    if (g0 < n_nodes) {
#pragma unroll
      for (int jj = 0; jj < 16; ++jj)
        PQ[(size_t)g0 * 256 + og + 16 * jj] = acc0[jj];
    }
    if (g1 < n_nodes) {
#pragma unroll
      for (int jj = 0; jj < 16; ++jj)
        PQ[(size_t)g1 * 256 + og + 16 * jj] = acc1[jj];
    }
  }
}

// ---------------------------------------------------------------------------
// Kernel B: per edge  hidden = relu(P[src]+Q[dst]); logits = hidden@W2.T+b2;
//           softmax -> out[e][0..7].  16 lanes per edge, lane owns k-slice of 8.
// ---------------------------------------------------------------------------
__global__ __launch_bounds__(256) void edge_mlp_kernel(
    const float* __restrict__ PQ, const int* __restrict__ src,
    const int* __restrict__ dst, const float* __restrict__ W2,
    const float* __restrict__ b2, float* __restrict__ out, int n_edges)
{
  const int t = threadIdx.x;
  const int g = t & 15;                 // lane within 16-lane edge group
  const int stride = gridDim.x * 16;    // total edge groups

  // W2 slice for this lane's k-slice: w2r[type][kk], kk -> k = 8*g + kk
  float w2r[8][8];
#pragma unroll
  for (int tt = 0; tt < 8; ++tt) {
    const float4 x = *(const float4*)(W2 + tt * HF + 8 * g);
    const float4 y = *(const float4*)(W2 + tt * HF + 8 * g + 4);
    w2r[tt][0] = x.x; w2r[tt][1] = x.y; w2r[tt][2] = x.z; w2r[tt][3] = x.w;
    w2r[tt][4] = y.x; w2r[tt][5] = y.y; w2r[tt][6] = y.z; w2r[tt][7] = y.w;
  }
  float bb[8];
#pragma unroll
  for (int tt = 0; tt < 8; ++tt) bb[tt] = b2[tt];

  for (int e = blockIdx.x * 16 + (t >> 4); e < n_edges; e += stride) {
    const int s = src[e];
    const int d = dst[e];
    const float* Pp = PQ + (size_t)s * 256 + 8 * g;        // P part (has b1)
    const float* Qp = PQ + (size_t)d * 256 + HF + 8 * g;   // Q part
    const float4 p0 = *(const float4*)Pp;
    const float4 p1 = *(const float4*)(Pp + 4);
    const float4 q0 = *(const float4*)Qp;
    const float4 q1 = *(const float4*)(Qp + 4);

    float hd[8];
    hd[0] = fmaxf(p0.x + q0.x, 0.0f);
    hd[1] = fmaxf(p0.y + q0.y, 0.0f);
    hd[2] = fmaxf(p0.z + q0.z, 0.0f);
    hd[3] = fmaxf(p0.w + q0.w, 0.0f);
    hd[4] = fmaxf(p1.x + q1.x, 0.0f);
    hd[5] = fmaxf(p1.y + q1.y, 0.0f);
    hd[6] = fmaxf(p1.z + q1.z, 0.0f);
    hd[7] = fmaxf(p1.w + q1.w, 0.0f);

    float l[8];
#pragma unroll
    for (int tt = 0; tt < 8; ++tt) {
      float a = hd[0] * w2r[tt][0];
      a = fmaf(hd[1], w2r[tt][1], a);
      a = fmaf(hd[2], w2r[tt][2], a);
      a = fmaf(hd[3], w2r[tt][3], a);
      a = fmaf(hd[4], w2r[tt][4], a);
      a = fmaf(hd[5], w2r[tt][5], a);
      a = fmaf(hd[6], w2r[tt][6], a);
      a = fmaf(hd[7], w2r[tt][7], a);
      l[tt] = a;
    }

    // reduce partial logits across the 16-lane group
#pragma unroll
    for (int m = 1; m <= 8; m <<= 1) {
#pragma unroll
      for (int tt = 0; tt < 8; ++tt) l[tt] += __shfl_xor(l[tt], m, 64);
    }

#pragma unroll
    for (int tt = 0; tt < 8; ++tt) l[tt] += bb[tt];

    float mx = l[0];
#pragma unroll
    for (int tt = 1; tt < 8; ++tt) mx = fmaxf(mx, l[tt]);

    float sum = 0.0f;
#pragma unroll
    for (int tt = 0; tt < 8; ++tt) {
      l[tt] = __expf(l[tt] - mx);
      sum += l[tt];
    }
    const float inv = 1.0f / sum;

    if (g < 8) {  // lanes 0..7 of the group each store one type
      const float s0 = (g & 1) ? l[1] : l[0];
      const float s1 = (g & 1) ? l[3] : l[2];
      const float s2 = (g & 1) ? l[5] : l[4];
      const float s3 = (g & 1) ? l[7] : l[6];
      const float u0 = (g & 2) ? s1 : s0;
      const float u1 = (g & 2) ? s3 : s2;
      const float v  = (g & 4) ? u1 : u0;
      out[(size_t)e * NTY + g] = v * inv;
    }
  }
}

// ---------------------------------------------------------------------------
extern "C" void kernel_launch(void* const* d_in, const int* in_sizes, int n_in,
                              void* d_out, int out_size, void* d_ws, size_t ws_size,
                              hipStream_t stream) {
  const float* h   = (const float*)d_in[0];
  const int*   src = (const int*)d_in[1];
  const int*   dst = (const int*)d_in[2];
  const float* W1  = (const float*)d_in[3];
  const float* b1  = (const float*)d_in[4];
  const float* W2  = (const float*)d_in[5];
  const float* b2  = (const float*)d_in[6];
  float* out = (float*)d_out;

  const int n_nodes = in_sizes[0] / HF;   // 50000
  const int n_edges = in_sizes[1];        // 500000
  float* PQ = (float*)d_ws;               // [n_nodes][256] = 51.2 MB

  const int n_tiles = (n_nodes + 31) / 32;
  hipLaunchKernelGGL(node_pq_kernel, dim3(256), dim3(256), 0, stream,
                     h, W1, b1, PQ, n_nodes, n_tiles);
  hipLaunchKernelGGL(edge_mlp_kernel, dim3(2048), dim3(256), 0, stream,
                     PQ, src, dst, W2, b2, out, n_edges);
}

// Round 2
// 106.653 us; speedup vs baseline: 1.5804x; 1.5804x over previous
//
#include <hip/hip_runtime.h>
#include <hip/hip_bf16.h>
#include <cstdint>
#include <cstddef>

#define HF 128   // hidden feature dim
#define NTY 8    // edge types

typedef __attribute__((ext_vector_type(8))) short short8;   // 8 bf16 = 4 VGPRs
typedef __attribute__((ext_vector_type(4))) float f32x4;

__device__ __forceinline__ short f2bf(float x) {   // RNE float->bf16 (finite inputs)
  union { float f; unsigned u; } v; v.f = x;
  unsigned r = v.u + 0x7FFFu + ((v.u >> 16) & 1u);
  return (short)(r >> 16);
}
__device__ __forceinline__ float bf2f(short b) {
  union { unsigned u; float f; } v; v.u = ((unsigned)(unsigned short)b) << 16;
  return v.f;
}

// ---------------------------------------------------------------------------
// Kernel A (MFMA): PQ[n][j] = (j<128) ? h[n]@W1a.T + b1 : h[n]@W1b.T
//   A split hi+lo bf16 (2 MFMA passes, residual ~2^-18); W plain bf16.
//   Tile: 64 nodes x 256 outs, 256 thr = 4 waves, wave w owns cols 64w..64w+63.
//   LDS: Bs [256 j][128 k] bf16 64KB (staged once; persistent blocks)
//        As [2][64 r][128 k] bf16 32KB, both XOR-chunk swizzled (2-way max).
// ---------------------------------------------------------------------------
__global__ __launch_bounds__(256, 1) void node_pq_mfma(
    const float* __restrict__ h, const float* __restrict__ W1,
    const float* __restrict__ b1, float* __restrict__ PQ,
    int n_nodes, int n_tiles)
{
  __shared__ short Bs[256 * HF];       // 65536 B
  __shared__ short As[2][64 * HF];     // 32768 B
  const int t    = threadIdx.x;
  const int lane = t & 63;
  const int w    = t >> 6;             // wave id 0..3
  const int cl   = lane & 15;          // col/row within 16x16 tile
  const int kg   = lane >> 4;          // k-group 0..3 (k = 32*ks + 8*kg + i)

  // ---- stage W as bf16, swizzled: Bs[j][k] = B[k][j] (=W1 halves) ----
  {
    const int j = t;  // 0..255, one row per thread
    const float* src = (j < HF) ? (W1 + (size_t)j * 256)
                                : (W1 + (size_t)(j - HF) * 256 + HF);
#pragma unroll
    for (int c = 0; c < 16; ++c) {     // chunk = 8 k-values
      const float4 x = *(const float4*)(src + 8 * c);
      const float4 y = *(const float4*)(src + 8 * c + 4);
      short8 b;
      b[0]=f2bf(x.x); b[1]=f2bf(x.y); b[2]=f2bf(x.z); b[3]=f2bf(x.w);
      b[4]=f2bf(y.x); b[5]=f2bf(y.y); b[6]=f2bf(y.z); b[7]=f2bf(y.w);
      *(short8*)(&Bs[j * HF + ((c ^ (j & 7)) << 3)]) = b;
    }
  }

  // ---- A-tile staging helpers (reg-staged: load early, cvt+write late) ----
  const int ar = t >> 2;               // row 0..63
  const int aq = t & 3;                // k-quarter (32 k)
  float4 pf[8];                        // prefetch regs: 32 floats

  auto loadA = [&](int tile) {
    int node = tile * 64 + ar;
    if (node >= n_nodes) node = n_nodes - 1;
    const float* p = h + (size_t)node * HF + 32 * aq;
#pragma unroll
    for (int i = 0; i < 8; ++i) pf[i] = *(const float4*)(p + 4 * i);
  };
  auto writeA = [&]() {
#pragma unroll
    for (int ci = 0; ci < 4; ++ci) {
      const int c = 4 * aq + ci;
      const float4 x = pf[2 * ci], y = pf[2 * ci + 1];
      float f[8] = {x.x, x.y, x.z, x.w, y.x, y.y, y.z, y.w};
      short8 hi, lo;
#pragma unroll
      for (int i = 0; i < 8; ++i) {
        const short hb = f2bf(f[i]);
        hi[i] = hb;
        lo[i] = f2bf(f[i] - bf2f(hb));
      }
      const int off = ar * HF + ((c ^ (ar & 7)) << 3);
      *(short8*)(&As[0][off]) = hi;
      *(short8*)(&As[1][off]) = lo;
    }
  };

  // per-wave bias (cols j = 64w + 16ni + cl; only j<128 has b1)
  float bias[4];
#pragma unroll
  for (int ni = 0; ni < 4; ++ni) {
    const int j = 64 * w + 16 * ni + cl;
    bias[ni] = (j < HF) ? b1[j] : 0.0f;
  }

  int tile = blockIdx.x;
  if (tile < n_tiles) { loadA(tile); writeA(); }
  __syncthreads();

  for (; tile < n_tiles; tile += gridDim.x) {
    int nxt = tile + gridDim.x;
    if (nxt >= n_tiles) nxt = tile;    // dummy reload on last iter
    loadA(nxt);                        // issue early; lands under compute

    f32x4 acc[4][4];
#pragma unroll
    for (int mi = 0; mi < 4; ++mi)
#pragma unroll
      for (int ni = 0; ni < 4; ++ni)
        acc[mi][ni] = f32x4{bias[ni], bias[ni], bias[ni], bias[ni]};

#pragma unroll
    for (int ks = 0; ks < 4; ++ks) {
      const int kc = ks * 4 + kg;      // frag chunk index
      short8 ah[4], al[4], bb[4];
#pragma unroll
      for (int mi = 0; mi < 4; ++mi) {
        const int r = 16 * mi + cl;
        const int off = r * HF + ((kc ^ (r & 7)) << 3);
        ah[mi] = *(const short8*)(&As[0][off]);
        al[mi] = *(const short8*)(&As[1][off]);
      }
#pragma unroll
      for (int ni = 0; ni < 4; ++ni) {
        const int j = 64 * w + 16 * ni + cl;
        bb[ni] = *(const short8*)(&Bs[j * HF + ((kc ^ (j & 7)) << 3)]);
      }
#pragma unroll
      for (int mi = 0; mi < 4; ++mi)
#pragma unroll
        for (int ni = 0; ni < 4; ++ni) {
          acc[mi][ni] = __builtin_amdgcn_mfma_f32_16x16x32_bf16(ah[mi], bb[ni], acc[mi][ni], 0, 0, 0);
          acc[mi][ni] = __builtin_amdgcn_mfma_f32_16x16x32_bf16(al[mi], bb[ni], acc[mi][ni], 0, 0, 0);
        }
    }

    // store C (col = cl, rows = 16mi + 4kg + reg)
#pragma unroll
    for (int mi = 0; mi < 4; ++mi) {
      const int rb = tile * 64 + 16 * mi + 4 * kg;
#pragma unroll
      for (int ni = 0; ni < 4; ++ni) {
        const int j = 64 * w + 16 * ni + cl;
#pragma unroll
        for (int reg = 0; reg < 4; ++reg) {
          const int node = rb + reg;
          if (node < n_nodes) PQ[(size_t)node * 256 + j] = acc[mi][ni][reg];
        }
      }
    }

    __syncthreads();   // all waves done reading As
    writeA();          // cvt + ds_write next tile (waits on pf loads)
    __syncthreads();
  }
}

// ---------------------------------------------------------------------------
// Kernel B: per edge  hidden = relu(P[src]+Q[dst]); logits = hidden@W2.T+b2;
//           softmax -> out[e][0..7].  16 lanes per edge, lane owns k-slice of 8.
// ---------------------------------------------------------------------------
__global__ __launch_bounds__(256) void edge_mlp_kernel(
    const float* __restrict__ PQ, const int* __restrict__ src,
    const int* __restrict__ dst, const float* __restrict__ W2,
    const float* __restrict__ b2, float* __restrict__ out, int n_edges)
{
  const int t = threadIdx.x;
  const int g = t & 15;                 // lane within 16-lane edge group
  const int stride = gridDim.x * 16;    // total edge groups

  float w2r[8][8];
#pragma unroll
  for (int tt = 0; tt < 8; ++tt) {
    const float4 x = *(const float4*)(W2 + tt * HF + 8 * g);
    const float4 y = *(const float4*)(W2 + tt * HF + 8 * g + 4);
    w2r[tt][0] = x.x; w2r[tt][1] = x.y; w2r[tt][2] = x.z; w2r[tt][3] = x.w;
    w2r[tt][4] = y.x; w2r[tt][5] = y.y; w2r[tt][6] = y.z; w2r[tt][7] = y.w;
  }
  float bb[8];
#pragma unroll
  for (int tt = 0; tt < 8; ++tt) bb[tt] = b2[tt];

  for (int e = blockIdx.x * 16 + (t >> 4); e < n_edges; e += stride) {
    const int s = src[e];
    const int d = dst[e];
    const float* Pp = PQ + (size_t)s * 256 + 8 * g;        // P part (has b1)
    const float* Qp = PQ + (size_t)d * 256 + HF + 8 * g;   // Q part
    const float4 p0 = *(const float4*)Pp;
    const float4 p1 = *(const float4*)(Pp + 4);
    const float4 q0 = *(const float4*)Qp;
    const float4 q1 = *(const float4*)(Qp + 4);

    float hd[8];
    hd[0] = fmaxf(p0.x + q0.x, 0.0f);
    hd[1] = fmaxf(p0.y + q0.y, 0.0f);
    hd[2] = fmaxf(p0.z + q0.z, 0.0f);
    hd[3] = fmaxf(p0.w + q0.w, 0.0f);
    hd[4] = fmaxf(p1.x + q1.x, 0.0f);
    hd[5] = fmaxf(p1.y + q1.y, 0.0f);
    hd[6] = fmaxf(p1.z + q1.z, 0.0f);
    hd[7] = fmaxf(p1.w + q1.w, 0.0f);

    float l[8];
#pragma unroll
    for (int tt = 0; tt < 8; ++tt) {
      float a = hd[0] * w2r[tt][0];
      a = fmaf(hd[1], w2r[tt][1], a);
      a = fmaf(hd[2], w2r[tt][2], a);
      a = fmaf(hd[3], w2r[tt][3], a);
      a = fmaf(hd[4], w2r[tt][4], a);
      a = fmaf(hd[5], w2r[tt][5], a);
      a = fmaf(hd[6], w2r[tt][6], a);
      a = fmaf(hd[7], w2r[tt][7], a);
      l[tt] = a;
    }

    // reduce partial logits across the 16-lane group
#pragma unroll
    for (int m = 1; m <= 8; m <<= 1) {
#pragma unroll
      for (int tt = 0; tt < 8; ++tt) l[tt] += __shfl_xor(l[tt], m, 64);
    }

#pragma unroll
    for (int tt = 0; tt < 8; ++tt) l[tt] += bb[tt];

    float mx = l[0];
#pragma unroll
    for (int tt = 1; tt < 8; ++tt) mx = fmaxf(mx, l[tt]);

    float sum = 0.0f;
#pragma unroll
    for (int tt = 0; tt < 8; ++tt) {
      l[tt] = __expf(l[tt] - mx);
      sum += l[tt];
    }
    const float inv = 1.0f / sum;

    if (g < 8) {  // lanes 0..7 of the group each store one type
      const float s0 = (g & 1) ? l[1] : l[0];
      const float s1 = (g & 1) ? l[3] : l[2];
      const float s2 = (g & 1) ? l[5] : l[4];
      const float s3 = (g & 1) ? l[7] : l[6];
      const float u0 = (g & 2) ? s1 : s0;
      const float u1 = (g & 2) ? s3 : s2;
      const float v  = (g & 4) ? u1 : u0;
      out[(size_t)e * NTY + g] = v * inv;
    }
  }
}

// ---------------------------------------------------------------------------
extern "C" void kernel_launch(void* const* d_in, const int* in_sizes, int n_in,
                              void* d_out, int out_size, void* d_ws, size_t ws_size,
                              hipStream_t stream) {
  const float* h   = (const float*)d_in[0];
  const int*   src = (const int*)d_in[1];
  const int*   dst = (const int*)d_in[2];
  const float* W1  = (const float*)d_in[3];
  const float* b1  = (const float*)d_in[4];
  const float* W2  = (const float*)d_in[5];
  const float* b2  = (const float*)d_in[6];
  float* out = (float*)d_out;

  const int n_nodes = in_sizes[0] / HF;   // 50000
  const int n_edges = in_sizes[1];        // 500000
  float* PQ = (float*)d_ws;               // [n_nodes][256] = 51.2 MB

  const int n_tiles = (n_nodes + 63) / 64;
  hipLaunchKernelGGL(node_pq_mfma, dim3(256), dim3(256), 0, stream,
                     h, W1, b1, PQ, n_nodes, n_tiles);
  hipLaunchKernelGGL(edge_mlp_kernel, dim3(2048), dim3(256), 0, stream,
                     PQ, src, dst, W2, b2, out, n_edges);
}

// Round 3
// 79.473 us; speedup vs baseline: 2.1208x; 1.3420x over previous
//
#include <hip/hip_runtime.h>
#include <cstdint>
#include <cstddef>

#define HF 128   // hidden feature dim
#define NTY 8    // edge types

typedef __attribute__((ext_vector_type(8))) short short8;   // 8 bf16 = 4 VGPRs
typedef __attribute__((ext_vector_type(4))) float f32x4;
typedef unsigned int u32;
typedef unsigned short u16;

__device__ __forceinline__ short f2bf(float x) {   // RNE float->bf16 (finite inputs)
  union { float f; unsigned u; } v; v.f = x;
  unsigned r = v.u + 0x7FFFu + ((v.u >> 16) & 1u);
  return (short)(r >> 16);
}
__device__ __forceinline__ float bf2f(short b) {
  union { unsigned u; float f; } v; v.u = ((unsigned)(unsigned short)b) << 16;
  return v.f;
}
__device__ __forceinline__ float bflo(u32 u) {     // low bf16 of a packed pair
  union { u32 x; float f; } v; v.x = u << 16; return v.f;
}
__device__ __forceinline__ float bfhi(u32 u) {     // high bf16 of a packed pair
  union { u32 x; float f; } v; v.x = u & 0xFFFF0000u; return v.f;
}

// ---------------------------------------------------------------------------
// Kernel A (MFMA): PQ[n][j] = bf16( (j<128) ? h[n]@W1a.T + b1 : h[n]@W1b.T )
//   A split hi+lo bf16 (2 MFMA passes); W plain bf16. Output stored bf16.
// ---------------------------------------------------------------------------
__global__ __launch_bounds__(256, 1) void node_pq_mfma(
    const float* __restrict__ h, const float* __restrict__ W1,
    const float* __restrict__ b1, u16* __restrict__ PQ,
    int n_nodes, int n_tiles)
{
  __shared__ short Bs[256 * HF];       // 65536 B
  __shared__ short As[2][64 * HF];     // 32768 B
  const int t    = threadIdx.x;
  const int lane = t & 63;
  const int w    = t >> 6;             // wave id 0..3
  const int cl   = lane & 15;          // col/row within 16x16 tile
  const int kg   = lane >> 4;          // k-group 0..3

  // ---- stage W as bf16, swizzled: Bs[j][k] = B[k][j] (=W1 halves) ----
  {
    const int j = t;  // 0..255
    const float* src = (j < HF) ? (W1 + (size_t)j * 256)
                                : (W1 + (size_t)(j - HF) * 256 + HF);
#pragma unroll
    for (int c = 0; c < 16; ++c) {
      const float4 x = *(const float4*)(src + 8 * c);
      const float4 y = *(const float4*)(src + 8 * c + 4);
      short8 b;
      b[0]=f2bf(x.x); b[1]=f2bf(x.y); b[2]=f2bf(x.z); b[3]=f2bf(x.w);
      b[4]=f2bf(y.x); b[5]=f2bf(y.y); b[6]=f2bf(y.z); b[7]=f2bf(y.w);
      *(short8*)(&Bs[j * HF + ((c ^ (j & 7)) << 3)]) = b;
    }
  }

  const int ar = t >> 2;               // row 0..63
  const int aq = t & 3;                // k-quarter (32 k)
  float4 pf[8];

  auto loadA = [&](int tile) {
    int node = tile * 64 + ar;
    if (node >= n_nodes) node = n_nodes - 1;
    const float* p = h + (size_t)node * HF + 32 * aq;
#pragma unroll
    for (int i = 0; i < 8; ++i) pf[i] = *(const float4*)(p + 4 * i);
  };
  auto writeA = [&]() {
#pragma unroll
    for (int ci = 0; ci < 4; ++ci) {
      const int c = 4 * aq + ci;
      const float4 x = pf[2 * ci], y = pf[2 * ci + 1];
      float f[8] = {x.x, x.y, x.z, x.w, y.x, y.y, y.z, y.w};
      short8 hi, lo;
#pragma unroll
      for (int i = 0; i < 8; ++i) {
        const short hb = f2bf(f[i]);
        hi[i] = hb;
        lo[i] = f2bf(f[i] - bf2f(hb));
      }
      const int off = ar * HF + ((c ^ (ar & 7)) << 3);
      *(short8*)(&As[0][off]) = hi;
      *(short8*)(&As[1][off]) = lo;
    }
  };

  float bias[4];
#pragma unroll
  for (int ni = 0; ni < 4; ++ni) {
    const int j = 64 * w + 16 * ni + cl;
    bias[ni] = (j < HF) ? b1[j] : 0.0f;
  }

  int tile = blockIdx.x;
  if (tile < n_tiles) { loadA(tile); writeA(); }
  __syncthreads();

  for (; tile < n_tiles; tile += gridDim.x) {
    int nxt = tile + gridDim.x;
    if (nxt >= n_tiles) nxt = tile;
    loadA(nxt);                        // issue early; lands under compute

    f32x4 acc[4][4];
#pragma unroll
    for (int mi = 0; mi < 4; ++mi)
#pragma unroll
      for (int ni = 0; ni < 4; ++ni)
        acc[mi][ni] = f32x4{bias[ni], bias[ni], bias[ni], bias[ni]};

#pragma unroll
    for (int ks = 0; ks < 4; ++ks) {
      const int kc = ks * 4 + kg;
      short8 ah[4], al[4], bb[4];
#pragma unroll
      for (int mi = 0; mi < 4; ++mi) {
        const int r = 16 * mi + cl;
        const int off = r * HF + ((kc ^ (r & 7)) << 3);
        ah[mi] = *(const short8*)(&As[0][off]);
        al[mi] = *(const short8*)(&As[1][off]);
      }
#pragma unroll
      for (int ni = 0; ni < 4; ++ni) {
        const int j = 64 * w + 16 * ni + cl;
        bb[ni] = *(const short8*)(&Bs[j * HF + ((kc ^ (j & 7)) << 3)]);
      }
#pragma unroll
      for (int mi = 0; mi < 4; ++mi)
#pragma unroll
        for (int ni = 0; ni < 4; ++ni) {
          acc[mi][ni] = __builtin_amdgcn_mfma_f32_16x16x32_bf16(ah[mi], bb[ni], acc[mi][ni], 0, 0, 0);
          acc[mi][ni] = __builtin_amdgcn_mfma_f32_16x16x32_bf16(al[mi], bb[ni], acc[mi][ni], 0, 0, 0);
        }
    }

    // store C as bf16 (col = cl, rows = 16mi + 4kg + reg)
#pragma unroll
    for (int mi = 0; mi < 4; ++mi) {
      const int rb = tile * 64 + 16 * mi + 4 * kg;
#pragma unroll
      for (int ni = 0; ni < 4; ++ni) {
        const int j = 64 * w + 16 * ni + cl;
#pragma unroll
        for (int reg = 0; reg < 4; ++reg) {
          const int node = rb + reg;
          if (node < n_nodes)
            PQ[(size_t)node * 256 + j] = (u16)f2bf(acc[mi][ni][reg]);
        }
      }
    }

    __syncthreads();
    writeA();
    __syncthreads();
  }
}

// ---------------------------------------------------------------------------
// Kernel B: per edge  hidden = relu(P[src]+Q[dst]); logits = hidden@W2.T+b2;
//   softmax -> out[e][0..7]. 16 lanes/edge, bf16 gather, reduce-scatter
//   butterfly (8 shuffles), 2-edge unroll for MLP.
// ---------------------------------------------------------------------------
__global__ __launch_bounds__(256) void edge_mlp_bf16(
    const u16* __restrict__ PQ, const int* __restrict__ src,
    const int* __restrict__ dst, const float* __restrict__ W2,
    const float* __restrict__ b2, float* __restrict__ out, int n_edges)
{
  const int t  = threadIdx.x;
  const int g  = t & 15;                  // lane within 16-lane edge group
  const int gl = g & 7;
  const int idx = 4 * (gl & 1) + (gl & 2) + ((gl & 4) >> 2);  // my final logit
  const float bbias = b2[idx];

  // W2 slice for this lane's k-slice (k = 8*g + kk)
  float w2r[8][8];
#pragma unroll
  for (int tt = 0; tt < 8; ++tt) {
    const float4 x = *(const float4*)(W2 + tt * HF + 8 * g);
    const float4 y = *(const float4*)(W2 + tt * HF + 8 * g + 4);
    w2r[tt][0] = x.x; w2r[tt][1] = x.y; w2r[tt][2] = x.z; w2r[tt][3] = x.w;
    w2r[tt][4] = y.x; w2r[tt][5] = y.y; w2r[tt][6] = y.z; w2r[tt][7] = y.w;
  }

  auto process = [&](uint4 Pv, uint4 Qv, int e, bool st) {
    const u32 pu[4] = {Pv.x, Pv.y, Pv.z, Pv.w};
    const u32 qu[4] = {Qv.x, Qv.y, Qv.z, Qv.w};
    float hd[8];
#pragma unroll
    for (int i = 0; i < 4; ++i) {
      hd[2 * i]     = fmaxf(bflo(pu[i]) + bflo(qu[i]), 0.0f);
      hd[2 * i + 1] = fmaxf(bfhi(pu[i]) + bfhi(qu[i]), 0.0f);
    }
    float l[8];
#pragma unroll
    for (int tt = 0; tt < 8; ++tt) {
      float a = hd[0] * w2r[tt][0];
      a = fmaf(hd[1], w2r[tt][1], a);
      a = fmaf(hd[2], w2r[tt][2], a);
      a = fmaf(hd[3], w2r[tt][3], a);
      a = fmaf(hd[4], w2r[tt][4], a);
      a = fmaf(hd[5], w2r[tt][5], a);
      a = fmaf(hd[6], w2r[tt][6], a);
      a = fmaf(hd[7], w2r[tt][7], a);
      l[tt] = a;
    }
    // reduce-scatter butterfly: 8 values over 16 lanes in 8 shuffles
    float s4[4];
#pragma unroll
    for (int i = 0; i < 4; ++i) {
      const float give = (g & 1) ? l[i] : l[i + 4];
      const float got  = __shfl_xor(give, 1, 64);
      s4[i] = ((g & 1) ? l[i + 4] : l[i]) + got;
    }
    float s2[2];
#pragma unroll
    for (int i = 0; i < 2; ++i) {
      const float give = (g & 2) ? s4[i] : s4[i + 2];
      const float got  = __shfl_xor(give, 2, 64);
      s2[i] = ((g & 2) ? s4[i + 2] : s4[i]) + got;
    }
    float L;
    {
      const float give = (g & 4) ? s2[0] : s2[1];
      const float got  = __shfl_xor(give, 4, 64);
      L = ((g & 4) ? s2[1] : s2[0]) + got;
    }
    L += __shfl_xor(L, 8, 64);   // sum the two 8-lane halves
    L += bbias;
    // softmax across the 8 distinct logits (lanes 0..7 / 8..15 mirrored)
    float m = fmaxf(L, __shfl_xor(L, 1, 64));
    m = fmaxf(m, __shfl_xor(m, 2, 64));
    m = fmaxf(m, __shfl_xor(m, 4, 64));
    const float ex = __expf(L - m);
    float sm = ex + __shfl_xor(ex, 1, 64);
    sm += __shfl_xor(sm, 2, 64);
    sm += __shfl_xor(sm, 4, 64);
    if (st && g < 8) out[(size_t)e * NTY + idx] = ex / sm;
  };

  const int grp  = blockIdx.x * 16 + (t >> 4);
  const int ngrp = gridDim.x * 16;

  for (int e0 = grp * 2; e0 < n_edges; e0 += ngrp * 2) {
    const bool has1 = (e0 + 1) < n_edges;
    const int e1 = has1 ? e0 + 1 : e0;
    const int s0 = src[e0], d0 = dst[e0];
    const int s1 = src[e1], d1 = dst[e1];
    const uint4 P0 = *(const uint4*)(PQ + (size_t)s0 * 256 + 8 * g);
    const uint4 Q0 = *(const uint4*)(PQ + (size_t)d0 * 256 + HF + 8 * g);
    const uint4 P1 = *(const uint4*)(PQ + (size_t)s1 * 256 + 8 * g);
    const uint4 Q1 = *(const uint4*)(PQ + (size_t)d1 * 256 + HF + 8 * g);
    process(P0, Q0, e0, true);
    process(P1, Q1, e1, has1);
  }
}

// ---------------------------------------------------------------------------
extern "C" void kernel_launch(void* const* d_in, const int* in_sizes, int n_in,
                              void* d_out, int out_size, void* d_ws, size_t ws_size,
                              hipStream_t stream) {
  const float* h   = (const float*)d_in[0];
  const int*   src = (const int*)d_in[1];
  const int*   dst = (const int*)d_in[2];
  const float* W1  = (const float*)d_in[3];
  const float* b1  = (const float*)d_in[4];
  const float* W2  = (const float*)d_in[5];
  const float* b2  = (const float*)d_in[6];
  float* out = (float*)d_out;

  const int n_nodes = in_sizes[0] / HF;   // 50000
  const int n_edges = in_sizes[1];        // 500000
  u16* PQ = (u16*)d_ws;                   // [n_nodes][256] bf16 = 25.6 MB

  const int n_tiles = (n_nodes + 63) / 64;
  hipLaunchKernelGGL(node_pq_mfma, dim3(256), dim3(256), 0, stream,
                     h, W1, b1, PQ, n_nodes, n_tiles);
  hipLaunchKernelGGL(edge_mlp_bf16, dim3(4096), dim3(256), 0, stream,
                     PQ, src, dst, W2, b2, out, n_edges);
}

// Round 4
// 71.792 us; speedup vs baseline: 2.3478x; 1.1070x over previous
//
#include <hip/hip_runtime.h>
#include <cstdint>
#include <cstddef>

#define HF 128   // hidden feature dim
#define NTY 8    // edge types

typedef __attribute__((ext_vector_type(8))) short short8;     // 8 bf16
typedef __attribute__((ext_vector_type(8))) _Float16 half8;   // 8 fp16
typedef __attribute__((ext_vector_type(4))) float f32x4;
typedef unsigned int u32;
typedef unsigned short u16;

__device__ __forceinline__ short f2bf(float x) {   // RNE float->bf16
  union { float f; unsigned u; } v; v.f = x;
  unsigned r = v.u + 0x7FFFu + ((v.u >> 16) & 1u);
  return (short)(r >> 16);
}
__device__ __forceinline__ float bf2f(short b) {
  union { unsigned u; float f; } v; v.u = ((unsigned)(unsigned short)b) << 16;
  return v.f;
}
__device__ __forceinline__ u16 f2h(float x) {      // RNE float->fp16 bits
  union { _Float16 h; u16 u; } v; v.h = (_Float16)x; return v.u;
}
// packed fp16: relu(p + q) on 2 lanes-of-16b at once
__device__ __forceinline__ u32 pk_addrelu_f16(u32 p, u32 q) {
  u32 r;
  asm("v_pk_add_f16 %0, %1, %2" : "=v"(r) : "v"(p), "v"(q));
  asm("v_pk_max_f16 %0, %1, 0"  : "=v"(r) : "v"(r));
  return r;
}

// ---------------------------------------------------------------------------
// Kernel A (MFMA): PQ[n][j] = fp16( (j<128) ? h[n]@W1a.T + b1 : h[n]@W1b.T )
//   A split hi+lo bf16 (2 MFMA passes); W plain bf16. Output stored fp16.
// ---------------------------------------------------------------------------
__global__ __launch_bounds__(256, 1) void node_pq_mfma(
    const float* __restrict__ h, const float* __restrict__ W1,
    const float* __restrict__ b1, u16* __restrict__ PQ,
    int n_nodes, int n_tiles)
{
  __shared__ short Bs[256 * HF];       // 65536 B
  __shared__ short As[2][64 * HF];     // 32768 B
  const int t    = threadIdx.x;
  const int lane = t & 63;
  const int w    = t >> 6;
  const int cl   = lane & 15;
  const int kg   = lane >> 4;

  // ---- stage W as bf16, swizzled: Bs[j][k] = B[k][j] (=W1 halves) ----
  {
    const int j = t;
    const float* src = (j < HF) ? (W1 + (size_t)j * 256)
                                : (W1 + (size_t)(j - HF) * 256 + HF);
#pragma unroll
    for (int c = 0; c < 16; ++c) {
      const float4 x = *(const float4*)(src + 8 * c);
      const float4 y = *(const float4*)(src + 8 * c + 4);
      short8 b;
      b[0]=f2bf(x.x); b[1]=f2bf(x.y); b[2]=f2bf(x.z); b[3]=f2bf(x.w);
      b[4]=f2bf(y.x); b[5]=f2bf(y.y); b[6]=f2bf(y.z); b[7]=f2bf(y.w);
      *(short8*)(&Bs[j * HF + ((c ^ (j & 7)) << 3)]) = b;
    }
  }

  const int ar = t >> 2;
  const int aq = t & 3;
  float4 pf[8];

  auto loadA = [&](int tile) {
    int node = tile * 64 + ar;
    if (node >= n_nodes) node = n_nodes - 1;
    const float* p = h + (size_t)node * HF + 32 * aq;
#pragma unroll
    for (int i = 0; i < 8; ++i) pf[i] = *(const float4*)(p + 4 * i);
  };
  auto writeA = [&]() {
#pragma unroll
    for (int ci = 0; ci < 4; ++ci) {
      const int c = 4 * aq + ci;
      const float4 x = pf[2 * ci], y = pf[2 * ci + 1];
      float f[8] = {x.x, x.y, x.z, x.w, y.x, y.y, y.z, y.w};
      short8 hi, lo;
#pragma unroll
      for (int i = 0; i < 8; ++i) {
        const short hb = f2bf(f[i]);
        hi[i] = hb;
        lo[i] = f2bf(f[i] - bf2f(hb));
      }
      const int off = ar * HF + ((c ^ (ar & 7)) << 3);
      *(short8*)(&As[0][off]) = hi;
      *(short8*)(&As[1][off]) = lo;
    }
  };

  float bias[4];
#pragma unroll
  for (int ni = 0; ni < 4; ++ni) {
    const int j = 64 * w + 16 * ni + cl;
    bias[ni] = (j < HF) ? b1[j] : 0.0f;
  }

  int tile = blockIdx.x;
  if (tile < n_tiles) { loadA(tile); writeA(); }
  __syncthreads();

  for (; tile < n_tiles; tile += gridDim.x) {
    int nxt = tile + gridDim.x;
    if (nxt >= n_tiles) nxt = tile;
    loadA(nxt);                        // issue early; lands under compute

    f32x4 acc[4][4];
#pragma unroll
    for (int mi = 0; mi < 4; ++mi)
#pragma unroll
      for (int ni = 0; ni < 4; ++ni)
        acc[mi][ni] = f32x4{bias[ni], bias[ni], bias[ni], bias[ni]};

#pragma unroll
    for (int ks = 0; ks < 4; ++ks) {
      const int kc = ks * 4 + kg;
      short8 ah[4], al[4], bb[4];
#pragma unroll
      for (int mi = 0; mi < 4; ++mi) {
        const int r = 16 * mi + cl;
        const int off = r * HF + ((kc ^ (r & 7)) << 3);
        ah[mi] = *(const short8*)(&As[0][off]);
        al[mi] = *(const short8*)(&As[1][off]);
      }
#pragma unroll
      for (int ni = 0; ni < 4; ++ni) {
        const int j = 64 * w + 16 * ni + cl;
        bb[ni] = *(const short8*)(&Bs[j * HF + ((kc ^ (j & 7)) << 3)]);
      }
#pragma unroll
      for (int mi = 0; mi < 4; ++mi)
#pragma unroll
        for (int ni = 0; ni < 4; ++ni) {
          acc[mi][ni] = __builtin_amdgcn_mfma_f32_16x16x32_bf16(ah[mi], bb[ni], acc[mi][ni], 0, 0, 0);
          acc[mi][ni] = __builtin_amdgcn_mfma_f32_16x16x32_bf16(al[mi], bb[ni], acc[mi][ni], 0, 0, 0);
        }
    }

    // store C as fp16 (col = cl, rows = 16mi + 4kg + reg)
#pragma unroll
    for (int mi = 0; mi < 4; ++mi) {
      const int rb = tile * 64 + 16 * mi + 4 * kg;
#pragma unroll
      for (int ni = 0; ni < 4; ++ni) {
        const int j = 64 * w + 16 * ni + cl;
#pragma unroll
        for (int reg = 0; reg < 4; ++reg) {
          const int node = rb + reg;
          if (node < n_nodes)
            PQ[(size_t)node * 256 + j] = f2h(acc[mi][ni][reg]);
        }
      }
    }

    __syncthreads();
    writeA();
    __syncthreads();
  }
}

// ---------------------------------------------------------------------------
// Kernel B (MFMA): 16 edges per wave-tile.
//   lane(cl,kg): cl=edge-in-tile, kg=k-group. A-frag[ks] = relu(P+Q) fp16 for
//   k = 32ks+8kg..+7 (packed add/max). B-frag = W2 fp16 (types 0..7, pad 0).
//   C: col=type(cl), row=edge(4kg+reg). Softmax via xor-1/2/4 shuffles.
// ---------------------------------------------------------------------------
__global__ __launch_bounds__(256) void edge_mlp_mfma(
    const u16* __restrict__ PQ, const int* __restrict__ src,
    const int* __restrict__ dst, const float* __restrict__ W2,
    const float* __restrict__ b2, float* __restrict__ out, int n_edges)
{
  const int t    = threadIdx.x;
  const int lane = t & 63;
  const int cl   = lane & 15;
  const int kg   = lane >> 4;

  // B fragments: bf[ks][i] = W2[cl][32ks+8kg+i] (fp16), 0 for cl>=8
  half8 bf[4];
#pragma unroll
  for (int ks = 0; ks < 4; ++ks) {
    if (cl < NTY) {
      const float* wp = W2 + cl * HF + 32 * ks + 8 * kg;
      const float4 x = *(const float4*)wp;
      const float4 y = *(const float4*)(wp + 4);
      bf[ks][0]=(_Float16)x.x; bf[ks][1]=(_Float16)x.y;
      bf[ks][2]=(_Float16)x.z; bf[ks][3]=(_Float16)x.w;
      bf[ks][4]=(_Float16)y.x; bf[ks][5]=(_Float16)y.y;
      bf[ks][6]=(_Float16)y.z; bf[ks][7]=(_Float16)y.w;
    } else {
#pragma unroll
      for (int i = 0; i < 8; ++i) bf[ks][i] = (_Float16)0.0f;
    }
  }
  const float bbias = (cl < NTY) ? b2[cl] : 0.0f;

  const int gw = blockIdx.x * 4 + (t >> 6);   // global wave id
  const int nw = gridDim.x * 4;

  for (int base = gw * 16; base < n_edges; base += nw * 16) {
    int e = base + cl;
    if (e >= n_edges) e = n_edges - 1;
    const int s = src[e];
    const int d = dst[e];
    const u16* pr = PQ + (size_t)s * 256 + 8 * kg;        // P half-row chunk
    const u16* qr = PQ + (size_t)d * 256 + HF + 8 * kg;   // Q half-row chunk

    uint4 P[4], Q[4];
#pragma unroll
    for (int ks = 0; ks < 4; ++ks) P[ks] = *(const uint4*)(pr + 32 * ks);
#pragma unroll
    for (int ks = 0; ks < 4; ++ks) Q[ks] = *(const uint4*)(qr + 32 * ks);

    f32x4 acc = f32x4{0.0f, 0.0f, 0.0f, 0.0f};
#pragma unroll
    for (int ks = 0; ks < 4; ++ks) {
      union { u32 w[4]; half8 v; } a;
      a.w[0] = pk_addrelu_f16(P[ks].x, Q[ks].x);
      a.w[1] = pk_addrelu_f16(P[ks].y, Q[ks].y);
      a.w[2] = pk_addrelu_f16(P[ks].z, Q[ks].z);
      a.w[3] = pk_addrelu_f16(P[ks].w, Q[ks].w);
      acc = __builtin_amdgcn_mfma_f32_16x16x32_f16(a.v, bf[ks], acc, 0, 0, 0);
    }

    // per-reg softmax over the 8 types (lanes cl 0..7; 8..15 are zero-pad)
    float val[4];
#pragma unroll
    for (int r = 0; r < 4; ++r) {
      const float L = acc[r] + bbias;
      float m = fmaxf(L, __shfl_xor(L, 1, 64));
      m = fmaxf(m, __shfl_xor(m, 2, 64));
      m = fmaxf(m, __shfl_xor(m, 4, 64));
      const float ex = __expf(L - m);
      float sm = ex + __shfl_xor(ex, 1, 64);
      sm += __shfl_xor(sm, 2, 64);
      sm += __shfl_xor(sm, 4, 64);
      val[r] = ex / sm;
    }

    if (cl < NTY) {
#pragma unroll
      for (int r = 0; r < 4; ++r) {
        const int ee = base + 4 * kg + r;
        if (ee < n_edges) out[(size_t)ee * NTY + cl] = val[r];
      }
    }
  }
}

// ---------------------------------------------------------------------------
extern "C" void kernel_launch(void* const* d_in, const int* in_sizes, int n_in,
                              void* d_out, int out_size, void* d_ws, size_t ws_size,
                              hipStream_t stream) {
  const float* h   = (const float*)d_in[0];
  const int*   src = (const int*)d_in[1];
  const int*   dst = (const int*)d_in[2];
  const float* W1  = (const float*)d_in[3];
  const float* b1  = (const float*)d_in[4];
  const float* W2  = (const float*)d_in[5];
  const float* b2  = (const float*)d_in[6];
  float* out = (float*)d_out;

  const int n_nodes = in_sizes[0] / HF;   // 50000
  const int n_edges = in_sizes[1];        // 500000
  u16* PQ = (u16*)d_ws;                   // [n_nodes][256] fp16 = 25.6 MB

  const int n_tiles = (n_nodes + 63) / 64;
  hipLaunchKernelGGL(node_pq_mfma, dim3(256), dim3(256), 0, stream,
                     h, W1, b1, PQ, n_nodes, n_tiles);
  hipLaunchKernelGGL(edge_mlp_mfma, dim3(2048), dim3(256), 0, stream,
                     PQ, src, dst, W2, b2, out, n_edges);
}